// Round 12
// baseline (382.399 us; speedup 1.0000x reference)
//
#include <hip/hip_runtime.h>

#define HD 128

constexpr int T_NC = 100000;
constexpr int T_ND = 20000;
constexpr int T_NG = 50000;
constexpr int T_E  = 150000;
constexpr int T_EP = 100000;
constexpr int NMAT = 21;          // 2 proj + 8 Wl + 8 Wr + W_cd^T + 2 summed (Wr1+Wr3 per layer)
constexpr int DEGN = 2 * T_NC + T_ND + T_NG;   // 270000
constexpr int WIN_C = (T_NC + 31) / 32;        // 3125
constexpr int WIN_D = (T_ND + 31) / 32;        // 625
constexpr int WIN_G = (T_NG + 31) / 32;        // 1563

typedef __attribute__((ext_vector_type(8))) short   s16x8;
typedef __attribute__((ext_vector_type(8))) __bf16  bf16x8;
typedef __attribute__((ext_vector_type(4))) float   f32x4;

union Frag { s16x8 s; bf16x8 b; };

__device__ __forceinline__ float gelu_f(float x) {
    return 0.5f * x * (1.0f + erff(x * 0.70710678118654752f));
}

// ---------------- weight packing (once per launch) ----------------
// mat 18 = W_cd TRANSPOSED (for Q-side decoder: Q = hd @ W_cd^T)
__global__ void pack_weights(const float* __restrict__ proj_W,
                             const float* __restrict__ sage_Wl,
                             const float* __restrict__ sage_Wr,
                             const float* __restrict__ W_cd,
                             unsigned short* __restrict__ phi,
                             unsigned short* __restrict__ plo)
{
    int m = blockIdx.x;
    const float* W;
    const float* W2 = nullptr;
    bool transp = false;
    if (m < 2)        W = proj_W  + (size_t)m * HD * HD;
    else if (m < 10)  W = sage_Wl + (size_t)(m - 2) * HD * HD;
    else if (m < 18)  W = sage_Wr + (size_t)(m - 10) * HD * HD;
    else if (m == 18) { W = W_cd; transp = true; }
    else {
        int l = m - 19;
        W  = sage_Wr + (size_t)(l * 4 + 1) * HD * HD;
        W2 = sage_Wr + (size_t)(l * 4 + 3) * HD * HD;
    }

    int t = threadIdx.x;          // 256
    int kstep = t >> 6;
    int lane  = t & 63;
    int kbase = kstep * 32 + (lane >> 4) * 8;
    int c     = lane & 15;
    for (int cb = 0; cb < 8; ++cb) {
        int col = cb * 16 + c;
        size_t off = ((((size_t)m * 8 + cb) * 4 + kstep) * 64 + lane) * 8;
        #pragma unroll
        for (int j = 0; j < 8; ++j) {
            int k = kbase + j;
            float w = transp ? W[(size_t)col * HD + k] : W[(size_t)k * HD + col];
            if (W2) w += W2[(size_t)k * HD + col];
            __bf16 h = (__bf16)w;
            union { __bf16 b; unsigned short u; } ch, cl;
            ch.b = h;
            cl.b = (__bf16)(w - (float)h);
            phi[off + j] = ch.u;
            plo[off + j] = cl.u;
        }
    }
}

// ---------------- gene_emb fp32 -> bf16 plane (once) ----------------
__global__ void conv_gene(const float* __restrict__ src, unsigned short* __restrict__ dst)
{
    size_t i = (size_t)(blockIdx.x * blockDim.x + threadIdx.x) * 8;
    if (i >= (size_t)T_NG * HD) return;
    f32x4 a0 = *(const f32x4*)(src + i);
    f32x4 a1 = *(const f32x4*)(src + i + 4);
    Frag u;
    u.b[0] = (__bf16)a0.x; u.b[1] = (__bf16)a0.y; u.b[2] = (__bf16)a0.z; u.b[3] = (__bf16)a0.w;
    u.b[4] = (__bf16)a1.x; u.b[5] = (__bf16)a1.y; u.b[6] = (__bf16)a1.z; u.b[7] = (__bf16)a1.w;
    *(s16x8*)(dst + i) = u.s;
}

// ---------------- CSR build (concatenated across 4 edge types) ----------------
__global__ void edge_count4(const int* __restrict__ eA, const int* __restrict__ eB,
                            const int* __restrict__ eC, const int* __restrict__ eD,
                            int gPer, int* __restrict__ deg)
{
    int seg = blockIdx.x / gPer;
    int e = (blockIdx.x % gPer) * 256 + threadIdx.x;
    if (e >= T_E) return;
    const int* ei = seg == 0 ? eA : seg == 1 ? eB : seg == 2 ? eC : eD;
    int off = seg == 0 ? 0 : seg == 1 ? T_NC : seg == 2 ? 2 * T_NC : 2 * T_NC + T_ND;
    atomicAdd(&deg[off + ei[T_E + e]], 1);
}

__global__ void scan_local(const int* __restrict__ deg, int* __restrict__ rp,
                           int* __restrict__ bsum, int N)
{
    __shared__ int wtot[4];
    int t = threadIdx.x;
    int lane = t & 63, w = t >> 6;
    int base = blockIdx.x * 1024 + t * 4;
    int v[4];
    #pragma unroll
    for (int j = 0; j < 4; ++j) v[j] = (base + j < N) ? deg[base + j] : 0;
    int p1 = v[0] + v[1];
    int p2 = p1 + v[2];
    int total = p2 + v[3];
    int sc = total;
    #pragma unroll
    for (int o = 1; o < 64; o <<= 1) {
        int y = __shfl_up(sc, o);
        if (lane >= o) sc += y;
    }
    if (lane == 63) wtot[w] = sc;
    __syncthreads();
    int woff = 0;
    for (int i = 0; i < w; ++i) woff += wtot[i];
    int ex = woff + sc - total;
    if (base + 0 < N) rp[base + 0] = ex;
    if (base + 1 < N) rp[base + 1] = ex + v[0];
    if (base + 2 < N) rp[base + 2] = ex + p1;
    if (base + 3 < N) rp[base + 3] = ex + p2;
    if (t == 255) bsum[blockIdx.x] = woff + sc;
}

__global__ void scan_tops(int* __restrict__ bsum, int B)
{
    int lane = threadIdx.x;  // 64
    int off = 0;
    for (int s = 0; s < B; s += 64) {
        int i = s + lane;
        int v = (i < B) ? bsum[i] : 0;
        int sc = v;
        #pragma unroll
        for (int o = 1; o < 64; o <<= 1) {
            int y = __shfl_up(sc, o);
            if (lane >= o) sc += y;
        }
        if (i < B) bsum[i] = off + sc - v;
        off += __shfl(sc, 63);
    }
}

__global__ void scan_add(int* __restrict__ rp, const int* __restrict__ bsum, int N)
{
    int base = blockIdx.x * 1024 + threadIdx.x * 4;
    int o = bsum[blockIdx.x];
    #pragma unroll
    for (int j = 0; j < 4; ++j)
        if (base + j < N) rp[base + j] += o;
}

__global__ void edge_fill4(const int* __restrict__ eA, const int* __restrict__ eB,
                           const int* __restrict__ eC, const int* __restrict__ eD,
                           int gPer, const int* __restrict__ rp,
                           int* __restrict__ fil, int* __restrict__ col)
{
    int seg = blockIdx.x / gPer;
    int e = (blockIdx.x % gPer) * 256 + threadIdx.x;
    if (e >= T_E) return;
    const int* ei = seg == 0 ? eA : seg == 1 ? eB : seg == 2 ? eC : eD;
    int off = seg == 0 ? 0 : seg == 1 ? T_NC : seg == 2 ? 2 * T_NC : 2 * T_NC + T_ND;
    int d = ei[T_E + e];
    int p = rp[off + d] + atomicAdd(&fil[off + d], 1);
    col[p] = ei[e];
}

// ---------------- per-32-window degree rank sort (deterministic, no scratch) ----------
// windows: [0,WIN_C) chem (key = deg_dc+deg_gc), [WIN_C,WIN_C+WIN_D) dis (deg_cd),
// rest gene (deg_cg). perm holds node ids, descending degree within each window.
__global__ void window_rank(const int* __restrict__ deg,
                            int* __restrict__ perm_c, int* __restrict__ perm_d,
                            int* __restrict__ perm_g)
{
    int gwin = (blockIdx.x * blockDim.x + threadIdx.x) >> 5;
    int lane = threadIdx.x & 63;
    int li = lane & 31;
    if (gwin >= WIN_C + WIN_D + WIN_G) return;
    int N, base; int* perm; int key = -1;
    if (gwin < WIN_C)              { N = T_NC; base = gwin * 32;            perm = perm_c; }
    else if (gwin < WIN_C + WIN_D) { N = T_ND; base = (gwin - WIN_C) * 32;  perm = perm_d; }
    else                           { N = T_NG; base = (gwin - WIN_C - WIN_D) * 32; perm = perm_g; }
    int i = base + li;
    if (i < N) {
        if (gwin < WIN_C)              key = deg[i] + deg[T_NC + i];
        else if (gwin < WIN_C + WIN_D) key = deg[2 * T_NC + i];
        else                           key = deg[2 * T_NC + T_ND + i];
    }
    int half = lane & 32;
    int rank = 0;
    #pragma unroll
    for (int j = 0; j < 32; ++j) {
        int kj = __shfl(key, half | j);
        rank += (kj > key) || (kj == key && j < li);
    }
    if (i < N) perm[base + rank] = i;
}

// ---------------- fused gather + multi-pair GEMM ----------------
struct Pair {
    const void* A;                 // f32 (fmt0) or bf16 plane (fmt1)
    const int* rp; const int* dg; const int* col;
    int w; int fmt;
};
struct Seg {
    Pair p0, p1, p2;
    const float *bias0, *bias1, *g_ln, *b_ln;
    unsigned short* out;
    const int* perm;               // row permutation (degree-equalized); null = identity
    float scale;
    int np, use_res, M, nblk;
};

template<int MODE>
__global__ __launch_bounds__(256, 8)
void fused_gemm(Seg s0, Seg s1, Seg s2,
                const unsigned short* __restrict__ phi,
                const unsigned short* __restrict__ plo)
{
    __shared__ __align__(16) unsigned short As_hi[32 * HD];
    __shared__ __align__(16) unsigned short As_lo[32 * HD];
    __shared__ float psum[4][32];
    __shared__ float psq[4][32];

    int bid = blockIdx.x;
    Seg s;
    if (bid < s0.nblk) s = s0;
    else if (bid < s0.nblk + s1.nblk) { bid -= s0.nblk; s = s1; }
    else { bid -= s0.nblk + s1.nblk; s = s2; }

    const int tid  = threadIdx.x;
    const int w    = tid >> 6;
    const int lane = tid & 63;
    const int c    = lane & 15;
    const int hi4  = lane >> 4;
    const int row0 = bid * 32;

    f32x4 acc[2][2];
    #pragma unroll
    for (int rb = 0; rb < 2; ++rb)
        #pragma unroll
        for (int q = 0; q < 2; ++q) acc[rb][q] = (f32x4)0.f;

    for (int p = 0; p < s.np; ++p) {
        Pair P = (p == 0) ? s.p0 : (p == 1) ? s.p1 : s.p2;
        const bool gath = (P.rp != nullptr);

        __syncthreads();   // protect LDS reuse from previous pair's reads
        for (int it = 0; it < 2; ++it) {
            int u  = tid + it * 256;
            int r  = u >> 4;
            int k8 = (u & 15) * 8;
            int gr0 = row0 + r;
            bool valid = gr0 < s.M;
            int gr = (valid && s.perm) ? s.perm[gr0] : gr0;
            Frag vh, vl;
            vh.s = (s16x8)0; vl.s = (s16x8)0;
            if (valid) {
                if (gath) {
                    float av[8] = {0.f, 0.f, 0.f, 0.f, 0.f, 0.f, 0.f, 0.f};
                    int st = P.rp[gr];
                    int d  = P.dg[gr];
                    const unsigned short* Ah = (const unsigned short*)P.A;
                    int i = 0;
                    for (; i + 2 <= d; i += 2) {
                        int e0 = P.col[st + i];
                        int e1 = P.col[st + i + 1];
                        Frag x0, x1;
                        x0.s = *(const s16x8*)(Ah + (size_t)e0 * HD + k8);
                        x1.s = *(const s16x8*)(Ah + (size_t)e1 * HD + k8);
                        #pragma unroll
                        for (int j = 0; j < 8; ++j)
                            av[j] += (float)x0.b[j] + (float)x1.b[j];
                    }
                    if (i < d) {
                        int e0 = P.col[st + i];
                        Frag x0;
                        x0.s = *(const s16x8*)(Ah + (size_t)e0 * HD + k8);
                        #pragma unroll
                        for (int j = 0; j < 8; ++j)
                            av[j] += (float)x0.b[j];
                    }
                    float rs = 1.f / (float)(d > 1 ? d : 1);
                    #pragma unroll
                    for (int j = 0; j < 8; ++j) {
                        float x = av[j] * rs;
                        __bf16 h = (__bf16)x;
                        vh.b[j] = h;
                        vl.b[j] = (__bf16)(x - (float)h);
                    }
                } else if (P.fmt) {
                    vh.s = *(const s16x8*)((const unsigned short*)P.A + (size_t)gr * HD + k8);
                } else {
                    const f32x4* ap = (const f32x4*)((const float*)P.A + (size_t)gr * HD + k8);
                    f32x4 a0 = ap[0], a1 = ap[1];
                    vh.b[0] = (__bf16)a0.x; vh.b[1] = (__bf16)a0.y;
                    vh.b[2] = (__bf16)a0.z; vh.b[3] = (__bf16)a0.w;
                    vh.b[4] = (__bf16)a1.x; vh.b[5] = (__bf16)a1.y;
                    vh.b[6] = (__bf16)a1.z; vh.b[7] = (__bf16)a1.w;
                }
            }
            int sidx = (r * HD + k8) ^ ((r & 7) << 3);
            *(s16x8*)(As_hi + sidx) = vh.s;
            if (gath) *(s16x8*)(As_lo + sidx) = vl.s;
        }
        __syncthreads();

        #pragma unroll
        for (int ks = 0; ks < 4; ++ks) {
            Frag bh[2], bl[2];
            #pragma unroll
            for (int q = 0; q < 2; ++q) {
                int cbG = w * 2 + q;
                size_t boff = ((((size_t)P.w * 8 + cbG) * 4 + ks) * 64 + lane) * 8;
                bh[q].s = *(const s16x8*)(phi + boff);
                bl[q].s = *(const s16x8*)(plo + boff);
            }
            #pragma unroll
            for (int rb = 0; rb < 2; ++rb) {
                int r = rb * 16 + c;
                int sidx = (r * HD + ks * 32 + hi4 * 8) ^ ((r & 7) << 3);
                Frag ah;
                ah.s = *(const s16x8*)(As_hi + sidx);
                #pragma unroll
                for (int q = 0; q < 2; ++q) {
                    acc[rb][q] = __builtin_amdgcn_mfma_f32_16x16x32_bf16(ah.b, bh[q].b, acc[rb][q], 0, 0, 0);
                    acc[rb][q] = __builtin_amdgcn_mfma_f32_16x16x32_bf16(ah.b, bl[q].b, acc[rb][q], 0, 0, 0);
                }
                if (gath) {
                    Frag al;
                    al.s = *(const s16x8*)(As_lo + sidx);
                    #pragma unroll
                    for (int q = 0; q < 2; ++q)
                        acc[rb][q] = __builtin_amdgcn_mfma_f32_16x16x32_bf16(al.b, bh[q].b, acc[rb][q], 0, 0, 0);
                }
            }
        }
    }

    // lane layout: col = (w*2+q)*16 + c ; row = rb*16 + hi4*4 + reg
    if (MODE == 0) {
        __syncthreads();
        #pragma unroll
        for (int rb = 0; rb < 2; ++rb)
            #pragma unroll
            for (int q = 0; q < 2; ++q) {
                int col = (w * 2 + q) * 16 + c;
                #pragma unroll
                for (int reg = 0; reg < 4; ++reg) {
                    int row = rb * 16 + hi4 * 4 + reg;
                    union { __bf16 b; unsigned short u; } cv;
                    cv.b = (__bf16)acc[rb][q][reg];
                    As_hi[row * HD + col] = cv.u;
                }
            }
        __syncthreads();
        int row = tid >> 3;
        int c8  = (tid & 7) * 8;
        int gr0 = row0 + row;
        if (gr0 < s.M) {
            int gr = s.perm ? s.perm[gr0] : gr0;
            *(s16x8*)(s.out + (size_t)gr * HD + c8)      = *(const s16x8*)(As_hi + row * HD + c8);
            *(s16x8*)(s.out + (size_t)gr * HD + 64 + c8) = *(const s16x8*)(As_hi + row * HD + 64 + c8);
        }
        return;
    }

    float bsum_[2], gl[2], bb[2];
    #pragma unroll
    for (int q = 0; q < 2; ++q) {
        int col = (w * 2 + q) * 16 + c;
        float b = 0.f;
        if (s.bias0) b += s.bias0[col];
        if (s.bias1) b += s.bias1[col];
        bsum_[q] = b;
        gl[q] = s.g_ln[col];
        bb[q] = s.b_ln[col];
    }

    float v[2][2][4];
    #pragma unroll
    for (int rb = 0; rb < 2; ++rb)
        #pragma unroll
        for (int q = 0; q < 2; ++q) {
            int col = (w * 2 + q) * 16 + c;
            #pragma unroll
            for (int reg = 0; reg < 4; ++reg) {
                int row = rb * 16 + hi4 * 4 + reg;
                float r_ = 0.f;
                if (s.use_res) {
                    int sx = (row * HD + col) ^ ((row & 7) << 3);
                    union { __bf16 b; unsigned short u; } cb; cb.u = As_hi[sx];
                    r_ = (float)cb.b;
                }
                v[rb][q][reg] = (acc[rb][q][reg] + bsum_[q]) * s.scale + r_;
            }
        }

    #pragma unroll
    for (int rb = 0; rb < 2; ++rb)
        #pragma unroll
        for (int reg = 0; reg < 4; ++reg) {
            float sm = v[rb][0][reg] + v[rb][1][reg];
            float qq = v[rb][0][reg] * v[rb][0][reg] + v[rb][1][reg] * v[rb][1][reg];
            #pragma unroll
            for (int m = 1; m <= 8; m <<= 1) {
                sm += __shfl_xor(sm, m);
                qq += __shfl_xor(qq, m);
            }
            if (c == 0) {
                int row = rb * 16 + hi4 * 4 + reg;
                psum[w][row] = sm;
                psq[w][row]  = qq;
            }
        }
    __syncthreads();

    #pragma unroll
    for (int rb = 0; rb < 2; ++rb)
        #pragma unroll
        for (int reg = 0; reg < 4; ++reg) {
            int row = rb * 16 + hi4 * 4 + reg;
            float S  = psum[0][row] + psum[1][row] + psum[2][row] + psum[3][row];
            float Q  = psq[0][row]  + psq[1][row]  + psq[2][row]  + psq[3][row];
            float mean = S * (1.f / 128.f);
            float var  = Q * (1.f / 128.f) - mean * mean;
            float rstd = rsqrtf(var + 1e-5f);
            #pragma unroll
            for (int q = 0; q < 2; ++q) {
                int col = (w * 2 + q) * 16 + c;
                float t = (v[rb][q][reg] - mean) * rstd * gl[q] + bb[q];
                union { __bf16 b; unsigned short u; } cv;
                cv.b = (__bf16)gelu_f(t);
                As_hi[row * HD + col] = cv.u;
            }
        }
    __syncthreads();

    {
        int row = tid >> 3;
        int c8  = (tid & 7) * 8;
        int gr0 = row0 + row;
        if (gr0 < s.M) {
            int gr = s.perm ? s.perm[gr0] : gr0;
            *(s16x8*)(s.out + (size_t)gr * HD + c8)      = *(const s16x8*)(As_hi + row * HD + c8);
            *(s16x8*)(s.out + (size_t)gr * HD + 64 + c8) = *(const s16x8*)(As_hi + row * HD + 64 + c8);
        }
    }
}

// merged pos+neg decoder: out[e] = dot(hc[src[e]], Q[dst[e]]) ; 16 lanes per edge
__global__ void edge_score2(const int* __restrict__ pos, const int* __restrict__ neg,
                            const unsigned short* __restrict__ Hc,
                            const unsigned short* __restrict__ Qb,
                            float* __restrict__ out)
{
    int t = blockIdx.x * blockDim.x + threadIdx.x;
    int e = t >> 4;
    if (e >= 2 * T_EP) return;
    int lane = t & 15;
    const int* ei = pos;
    float* o = out;
    if (e >= T_EP) { e -= T_EP; ei = neg; o = out + T_EP; }
    int sI = ei[e];
    int dI = ei[T_EP + e];
    Frag p, h;
    p.s = *(const s16x8*)(Hc + (size_t)sI * HD + lane * 8);
    h.s = *(const s16x8*)(Qb + (size_t)dI * HD + lane * 8);
    float acc = 0.f;
    #pragma unroll
    for (int j = 0; j < 8; ++j)
        acc += (float)p.b[j] * (float)h.b[j];
    #pragma unroll
    for (int m = 1; m <= 8; m <<= 1) acc += __shfl_xor(acc, m);
    if (lane == 0) o[e] = acc;
}

extern "C" void kernel_launch(void* const* d_in, const int* in_sizes, int n_in,
                              void* d_out, int out_size, void* d_ws, size_t ws_size,
                              hipStream_t stream)
{
    const float* x_chem    = (const float*)d_in[0];
    const float* x_dis     = (const float*)d_in[1];
    const float* gene_emb  = (const float*)d_in[2];
    const float* proj_W    = (const float*)d_in[3];
    const float* proj_b    = (const float*)d_in[4];
    const float* proj_ln_g = (const float*)d_in[5];
    const float* proj_ln_b = (const float*)d_in[6];
    const float* sage_Wl   = (const float*)d_in[7];
    const float* sage_bl   = (const float*)d_in[8];
    const float* sage_Wr   = (const float*)d_in[9];
    const float* ln_g      = (const float*)d_in[10];
    const float* ln_b      = (const float*)d_in[11];
    const float* W_cd      = (const float*)d_in[12];
    const int*   ei_c2d    = (const int*)d_in[13];
    const int*   ei_d2c    = (const int*)d_in[14];
    const int*   ei_c2g    = (const int*)d_in[15];
    const int*   ei_g2c    = (const int*)d_in[16];
    const int*   pos_edge  = (const int*)d_in[17];
    const int*   neg_edge  = (const int*)d_in[18];
    float* out = (float*)d_out;

    // ---- workspace layout (single bf16 plane per state, ping-pong) ----
    unsigned short* us = (unsigned short*)d_ws;
    const size_t SC = (size_t)T_NC * HD, SD = (size_t)T_ND * HD, SG = (size_t)T_NG * HD;
    unsigned short* hc0  = us;
    unsigned short* hc1  = hc0 + SC;
    unsigned short* hd0  = hc1 + SC;
    unsigned short* hd1  = hd0 + SD;
    unsigned short* hgA  = hd1 + SD;
    unsigned short* hgB  = hgA + SG;       // unused; kept for layout
    unsigned short* geneB = hgB + SG;      // bf16 of gene_emb
    unsigned short* packHi = geneB + SG;
    unsigned short* packLo = packHi + (size_t)NMAT * HD * HD;
    int* ib  = (int*)(packLo + (size_t)NMAT * HD * HD);
    int* deg = ib;                  // DEGN
    int* fil = deg + DEGN;          // DEGN
    int* rp  = fil + DEGN;          // DEGN
    int* col = rp + DEGN;           // 4E
    int* bsum = col + 4 * T_E;      // 512
    int* perm_c = bsum + 512;       // NC
    int* perm_d = perm_c + T_NC;    // ND
    int* perm_g = perm_d + T_ND;    // NG
    unsigned short* Qb = hd1;       // Q = hd_final @ W_cd^T ; hd1 free after layer 2

    const dim3 blk(256);
    const int gC = (T_NC + 31) / 32;   // 3125
    const int gD = (T_ND + 31) / 32;   // 625
    const int gG = (T_NG + 31) / 32;   // 1563
    const int gE256 = (T_E + 255) / 256;
    const int gScan = (DEGN + 1023) / 1024;
    const int gConv = (int)(((size_t)T_NG * HD / 8 + 255) / 256);
    const int gRank = ((WIN_C + WIN_D + WIN_G) * 32 + 255) / 256;
    const int OFF_DC = 0, OFF_GC = T_NC, OFF_CD = 2 * T_NC, OFF_CG = 2 * T_NC + T_ND;

    // ---- one-time: pack weights, convert gene, build concatenated CSR + perms ----
    pack_weights<<<NMAT, blk, 0, stream>>>(proj_W, sage_Wl, sage_Wr, W_cd, packHi, packLo);
    conv_gene<<<gConv, blk, 0, stream>>>(gene_emb, geneB);
    hipMemsetAsync(deg, 0, (size_t)2 * DEGN * sizeof(int), stream);  // deg + fil

    edge_count4<<<4 * gE256, blk, 0, stream>>>(ei_d2c, ei_g2c, ei_c2d, ei_c2g, gE256, deg);
    window_rank<<<gRank, blk, 0, stream>>>(deg, perm_c, perm_d, perm_g);
    scan_local<<<gScan, blk, 0, stream>>>(deg, rp, bsum, DEGN);
    scan_tops<<<1, 64, 0, stream>>>(bsum, gScan);
    scan_add<<<gScan, blk, 0, stream>>>(rp, bsum, DEGN);
    edge_fill4<<<4 * gE256, blk, 0, stream>>>(ei_d2c, ei_g2c, ei_c2d, ei_c2g, gE256, rp, fil, col);

    Seg z{};  // empty (nblk=0)

    // ---- projections (merged dispatch, identity perm) ----
    {
        Seg pc{};
        pc.p0.A = x_chem; pc.p0.w = 0; pc.p0.fmt = 0;
        pc.np = 1; pc.use_res = 0;
        pc.bias0 = proj_b; pc.g_ln = proj_ln_g; pc.b_ln = proj_ln_b;
        pc.scale = 1.f; pc.out = hc0; pc.M = T_NC; pc.nblk = gC;
        Seg pd{};
        pd.p0.A = x_dis; pd.p0.w = 1; pd.p0.fmt = 0;
        pd.np = 1; pd.use_res = 0;
        pd.bias0 = proj_b + HD; pd.g_ln = proj_ln_g + HD; pd.b_ln = proj_ln_b + HD;
        pd.scale = 1.f; pd.out = hd0; pd.M = T_ND; pd.nblk = gD;
        fused_gemm<1><<<gC + gD, blk, 0, stream>>>(pc, pd, z, packHi, packLo);
    }

    for (int l = 0; l < 2; ++l) {
        const float* bl = sage_bl + (size_t)l * 4 * HD;
        const float* lg = ln_g + (size_t)l * 3 * HD;
        const float* lb = ln_b + (size_t)l * 3 * HD;
        const int wl = 2 + l * 4;
        const int wr = 10 + l * 4;
        const int wsum = 19 + l;

        const unsigned short* hcC = (l == 0) ? hc0 : hc1;
        unsigned short*       hcN = (l == 0) ? hc1 : hc0;
        const unsigned short* hdC = (l == 0) ? hd0 : hd1;
        unsigned short*       hdN = (l == 0) ? hd1 : hd0;
        const unsigned short* hgC = (l == 0) ? geneB : hgA;

        // chem: 0.5*(mean_dc(hd)@Wl1 + bl1 + mean_gc(hg)@Wl3 + bl3 + hc@(Wr1+Wr3)) + hc
        Seg sc{};
        sc.p0.A = hdC; sc.p0.fmt = 1; sc.p0.rp = rp + OFF_DC; sc.p0.dg = deg + OFF_DC; sc.p0.col = col; sc.p0.w = wl + 1;
        sc.p1.A = hgC; sc.p1.fmt = 1; sc.p1.rp = rp + OFF_GC; sc.p1.dg = deg + OFF_GC; sc.p1.col = col; sc.p1.w = wl + 3;
        sc.p2.A = hcC; sc.p2.fmt = 1; sc.p2.w = wsum;
        sc.np = 3; sc.use_res = 1; sc.perm = perm_c;
        sc.bias0 = bl + 1 * HD; sc.bias1 = bl + 3 * HD;
        sc.scale = 0.5f; sc.g_ln = lg; sc.b_ln = lb;
        sc.out = hcN; sc.M = T_NC; sc.nblk = gC;

        // dis: mean_cd(hc)@Wl0 + bl0 + hd@Wr0 + hd
        Seg sd{};
        sd.p0.A = hcC; sd.p0.fmt = 1; sd.p0.rp = rp + OFF_CD; sd.p0.dg = deg + OFF_CD; sd.p0.col = col; sd.p0.w = wl + 0;
        sd.p1.A = hdC; sd.p1.fmt = 1; sd.p1.w = wr + 0;
        sd.np = 2; sd.use_res = 1; sd.perm = perm_d;
        sd.bias0 = bl + 0 * HD;
        sd.scale = 1.f; sd.g_ln = lg + HD; sd.b_ln = lb + HD;
        sd.out = hdN; sd.M = T_ND; sd.nblk = gD;

        if (l == 0) {
            // gene layer 0 only (layer-2 gene output is dead -> skipped)
            Seg sg{};
            sg.p0.A = hcC; sg.p0.fmt = 1; sg.p0.rp = rp + OFF_CG; sg.p0.dg = deg + OFF_CG; sg.p0.col = col; sg.p0.w = wl + 2;
            sg.p1.A = hgC; sg.p1.fmt = 1; sg.p1.w = wr + 2;
            sg.np = 2; sg.use_res = 1; sg.perm = perm_g;
            sg.bias0 = bl + 2 * HD;
            sg.scale = 1.f; sg.g_ln = lg + 2 * HD; sg.b_ln = lb + 2 * HD;
            sg.out = hgA; sg.M = T_NG; sg.nblk = gG;
            fused_gemm<1><<<gC + gD + gG, blk, 0, stream>>>(sc, sd, sg, packHi, packLo);
        } else {
            fused_gemm<1><<<gC + gD, blk, 0, stream>>>(sc, sd, z, packHi, packLo);
        }
    }

    // Q = hd_final @ W_cd^T  (hd_final = hd0; 625 blocks)
    {
        Seg sq{};
        sq.p0.A = hd0; sq.p0.fmt = 1; sq.p0.w = 18;
        sq.np = 1; sq.use_res = 0;
        sq.scale = 1.f; sq.out = Qb; sq.M = T_ND; sq.nblk = gD;
        fused_gemm<0><<<gD, blk, 0, stream>>>(sq, z, z, packHi, packLo);
    }

    const int gEdge = (2 * T_EP * 16 + 255) / 256;
    edge_score2<<<gEdge, blk, 0, stream>>>(pos_edge, neg_edge, hc0, Qb, out);
}

// Round 13
// 362.271 us; speedup vs baseline: 1.0556x; 1.0556x over previous
//
#include <hip/hip_runtime.h>

#define HD 128

constexpr int T_NC = 100000;
constexpr int T_ND = 20000;
constexpr int T_NG = 50000;
constexpr int T_E  = 150000;
constexpr int T_EP = 100000;
constexpr int NMAT = 21;          // 2 proj + 8 Wl + 8 Wr + W_cd^T + 2 summed (Wr1+Wr3 per layer)
constexpr int DEGN = 2 * T_NC + T_ND + T_NG;   // 270000

typedef __attribute__((ext_vector_type(8))) short   s16x8;
typedef __attribute__((ext_vector_type(8))) __bf16  bf16x8;
typedef __attribute__((ext_vector_type(4))) float   f32x4;

union Frag { s16x8 s; bf16x8 b; };

__device__ __forceinline__ float gelu_f(float x) {
    return 0.5f * x * (1.0f + erff(x * 0.70710678118654752f));
}

// ---------------- weight packing (once per launch) ----------------
// mat 18 = W_cd TRANSPOSED (for Q-side decoder: Q = hd @ W_cd^T)
__global__ void pack_weights(const float* __restrict__ proj_W,
                             const float* __restrict__ sage_Wl,
                             const float* __restrict__ sage_Wr,
                             const float* __restrict__ W_cd,
                             unsigned short* __restrict__ phi,
                             unsigned short* __restrict__ plo)
{
    int m = blockIdx.x;
    const float* W;
    const float* W2 = nullptr;
    bool transp = false;
    if (m < 2)        W = proj_W  + (size_t)m * HD * HD;
    else if (m < 10)  W = sage_Wl + (size_t)(m - 2) * HD * HD;
    else if (m < 18)  W = sage_Wr + (size_t)(m - 10) * HD * HD;
    else if (m == 18) { W = W_cd; transp = true; }
    else {
        int l = m - 19;
        W  = sage_Wr + (size_t)(l * 4 + 1) * HD * HD;
        W2 = sage_Wr + (size_t)(l * 4 + 3) * HD * HD;
    }

    int t = threadIdx.x;          // 256
    int kstep = t >> 6;
    int lane  = t & 63;
    int kbase = kstep * 32 + (lane >> 4) * 8;
    int c     = lane & 15;
    for (int cb = 0; cb < 8; ++cb) {
        int col = cb * 16 + c;
        size_t off = ((((size_t)m * 8 + cb) * 4 + kstep) * 64 + lane) * 8;
        #pragma unroll
        for (int j = 0; j < 8; ++j) {
            int k = kbase + j;
            float w = transp ? W[(size_t)col * HD + k] : W[(size_t)k * HD + col];
            if (W2) w += W2[(size_t)k * HD + col];
            __bf16 h = (__bf16)w;
            union { __bf16 b; unsigned short u; } ch, cl;
            ch.b = h;
            cl.b = (__bf16)(w - (float)h);
            phi[off + j] = ch.u;
            plo[off + j] = cl.u;
        }
    }
}

// ---------------- gene_emb fp32 -> bf16 plane (once) ----------------
__global__ void conv_gene(const float* __restrict__ src, unsigned short* __restrict__ dst)
{
    size_t i = (size_t)(blockIdx.x * blockDim.x + threadIdx.x) * 8;
    if (i >= (size_t)T_NG * HD) return;
    f32x4 a0 = *(const f32x4*)(src + i);
    f32x4 a1 = *(const f32x4*)(src + i + 4);
    Frag u;
    u.b[0] = (__bf16)a0.x; u.b[1] = (__bf16)a0.y; u.b[2] = (__bf16)a0.z; u.b[3] = (__bf16)a0.w;
    u.b[4] = (__bf16)a1.x; u.b[5] = (__bf16)a1.y; u.b[6] = (__bf16)a1.z; u.b[7] = (__bf16)a1.w;
    *(s16x8*)(dst + i) = u.s;
}

// ---------------- CSR build (concatenated across 4 edge types) ----------------
__global__ void edge_count4(const int* __restrict__ eA, const int* __restrict__ eB,
                            const int* __restrict__ eC, const int* __restrict__ eD,
                            int gPer, int* __restrict__ deg)
{
    int seg = blockIdx.x / gPer;
    int e = (blockIdx.x % gPer) * 256 + threadIdx.x;
    if (e >= T_E) return;
    const int* ei = seg == 0 ? eA : seg == 1 ? eB : seg == 2 ? eC : eD;
    int off = seg == 0 ? 0 : seg == 1 ? T_NC : seg == 2 ? 2 * T_NC : 2 * T_NC + T_ND;
    atomicAdd(&deg[off + ei[T_E + e]], 1);
}

__global__ void scan_local(const int* __restrict__ deg, int* __restrict__ rp,
                           int* __restrict__ bsum, int N)
{
    __shared__ int wtot[4];
    int t = threadIdx.x;
    int lane = t & 63, w = t >> 6;
    int base = blockIdx.x * 1024 + t * 4;
    int v[4];
    #pragma unroll
    for (int j = 0; j < 4; ++j) v[j] = (base + j < N) ? deg[base + j] : 0;
    int p1 = v[0] + v[1];
    int p2 = p1 + v[2];
    int total = p2 + v[3];
    int sc = total;
    #pragma unroll
    for (int o = 1; o < 64; o <<= 1) {
        int y = __shfl_up(sc, o);
        if (lane >= o) sc += y;
    }
    if (lane == 63) wtot[w] = sc;
    __syncthreads();
    int woff = 0;
    for (int i = 0; i < w; ++i) woff += wtot[i];
    int ex = woff + sc - total;
    if (base + 0 < N) rp[base + 0] = ex;
    if (base + 1 < N) rp[base + 1] = ex + v[0];
    if (base + 2 < N) rp[base + 2] = ex + p1;
    if (base + 3 < N) rp[base + 3] = ex + p2;
    if (t == 255) bsum[blockIdx.x] = woff + sc;
}

__global__ void scan_tops(int* __restrict__ bsum, int B)
{
    int lane = threadIdx.x;  // 64
    int off = 0;
    for (int s = 0; s < B; s += 64) {
        int i = s + lane;
        int v = (i < B) ? bsum[i] : 0;
        int sc = v;
        #pragma unroll
        for (int o = 1; o < 64; o <<= 1) {
            int y = __shfl_up(sc, o);
            if (lane >= o) sc += y;
        }
        if (i < B) bsum[i] = off + sc - v;
        off += __shfl(sc, 63);
    }
}

__global__ void scan_add(int* __restrict__ rp, const int* __restrict__ bsum, int N)
{
    int base = blockIdx.x * 1024 + threadIdx.x * 4;
    int o = bsum[blockIdx.x];
    #pragma unroll
    for (int j = 0; j < 4; ++j)
        if (base + j < N) rp[base + j] += o;
}

__global__ void edge_fill4(const int* __restrict__ eA, const int* __restrict__ eB,
                           const int* __restrict__ eC, const int* __restrict__ eD,
                           int gPer, const int* __restrict__ rp,
                           int* __restrict__ fil, int* __restrict__ col)
{
    int seg = blockIdx.x / gPer;
    int e = (blockIdx.x % gPer) * 256 + threadIdx.x;
    if (e >= T_E) return;
    const int* ei = seg == 0 ? eA : seg == 1 ? eB : seg == 2 ? eC : eD;
    int off = seg == 0 ? 0 : seg == 1 ? T_NC : seg == 2 ? 2 * T_NC : 2 * T_NC + T_ND;
    int d = ei[T_E + e];
    int p = rp[off + d] + atomicAdd(&fil[off + d], 1);
    col[p] = ei[e];
}

// ---------------- fused gather + multi-pair GEMM (round-9/11 staging, verified fast) ----------------
struct Pair {
    const void* A;                 // f32 (fmt0) or bf16 plane (fmt1)
    const int* rp; const int* dg; const int* col;
    int w; int fmt;
};
struct Seg {
    Pair p0, p1, p2;
    const float *bias0, *bias1, *g_ln, *b_ln;
    unsigned short* out;
    float scale;
    int np, use_res, M, nblk;
};

template<int MODE>
__global__ __launch_bounds__(256, 8)
void fused_gemm(Seg s0, Seg s1, Seg s2,
                const unsigned short* __restrict__ phi,
                const unsigned short* __restrict__ plo)
{
    __shared__ __align__(16) unsigned short As_hi[32 * HD];
    __shared__ __align__(16) unsigned short As_lo[32 * HD];
    __shared__ float psum[4][32];
    __shared__ float psq[4][32];

    int bid = blockIdx.x;
    Seg s;
    if (bid < s0.nblk) s = s0;
    else if (bid < s0.nblk + s1.nblk) { bid -= s0.nblk; s = s1; }
    else { bid -= s0.nblk + s1.nblk; s = s2; }

    const int tid  = threadIdx.x;
    const int w    = tid >> 6;
    const int lane = tid & 63;
    const int c    = lane & 15;
    const int hi4  = lane >> 4;
    const int row0 = bid * 32;

    f32x4 acc[2][2];
    #pragma unroll
    for (int rb = 0; rb < 2; ++rb)
        #pragma unroll
        for (int q = 0; q < 2; ++q) acc[rb][q] = (f32x4)0.f;

    for (int p = 0; p < s.np; ++p) {
        Pair P = (p == 0) ? s.p0 : (p == 1) ? s.p1 : s.p2;
        const bool gath = (P.rp != nullptr);

        __syncthreads();   // protect LDS reuse from previous pair's reads
        for (int it = 0; it < 2; ++it) {
            int u  = tid + it * 256;
            int r  = u >> 4;
            int k8 = (u & 15) * 8;
            int gr = row0 + r;
            Frag vh, vl;
            vh.s = (s16x8)0; vl.s = (s16x8)0;
            if (gr < s.M) {
                if (gath) {
                    float av[8] = {0.f, 0.f, 0.f, 0.f, 0.f, 0.f, 0.f, 0.f};
                    int st = P.rp[gr];
                    int d  = P.dg[gr];
                    const unsigned short* Ah = (const unsigned short*)P.A;
                    int i = 0;
                    for (; i + 2 <= d; i += 2) {
                        int e0 = P.col[st + i];
                        int e1 = P.col[st + i + 1];
                        Frag x0, x1;
                        x0.s = *(const s16x8*)(Ah + (size_t)e0 * HD + k8);
                        x1.s = *(const s16x8*)(Ah + (size_t)e1 * HD + k8);
                        #pragma unroll
                        for (int j = 0; j < 8; ++j)
                            av[j] += (float)x0.b[j] + (float)x1.b[j];
                    }
                    if (i < d) {
                        int e0 = P.col[st + i];
                        Frag x0;
                        x0.s = *(const s16x8*)(Ah + (size_t)e0 * HD + k8);
                        #pragma unroll
                        for (int j = 0; j < 8; ++j)
                            av[j] += (float)x0.b[j];
                    }
                    float rs = 1.f / (float)(d > 1 ? d : 1);
                    #pragma unroll
                    for (int j = 0; j < 8; ++j) {
                        float x = av[j] * rs;
                        __bf16 h = (__bf16)x;
                        vh.b[j] = h;
                        vl.b[j] = (__bf16)(x - (float)h);
                    }
                } else if (P.fmt) {
                    vh.s = *(const s16x8*)((const unsigned short*)P.A + (size_t)gr * HD + k8);
                } else {
                    const f32x4* ap = (const f32x4*)((const float*)P.A + (size_t)gr * HD + k8);
                    f32x4 a0 = ap[0], a1 = ap[1];
                    vh.b[0] = (__bf16)a0.x; vh.b[1] = (__bf16)a0.y;
                    vh.b[2] = (__bf16)a0.z; vh.b[3] = (__bf16)a0.w;
                    vh.b[4] = (__bf16)a1.x; vh.b[5] = (__bf16)a1.y;
                    vh.b[6] = (__bf16)a1.z; vh.b[7] = (__bf16)a1.w;
                }
            }
            int sidx = (r * HD + k8) ^ ((r & 7) << 3);
            *(s16x8*)(As_hi + sidx) = vh.s;
            if (gath) *(s16x8*)(As_lo + sidx) = vl.s;
        }
        __syncthreads();

        #pragma unroll
        for (int ks = 0; ks < 4; ++ks) {
            Frag bh[2], bl[2];
            #pragma unroll
            for (int q = 0; q < 2; ++q) {
                int cbG = w * 2 + q;
                size_t boff = ((((size_t)P.w * 8 + cbG) * 4 + ks) * 64 + lane) * 8;
                bh[q].s = *(const s16x8*)(phi + boff);
                bl[q].s = *(const s16x8*)(plo + boff);
            }
            #pragma unroll
            for (int rb = 0; rb < 2; ++rb) {
                int r = rb * 16 + c;
                int sidx = (r * HD + ks * 32 + hi4 * 8) ^ ((r & 7) << 3);
                Frag ah;
                ah.s = *(const s16x8*)(As_hi + sidx);
                #pragma unroll
                for (int q = 0; q < 2; ++q) {
                    acc[rb][q] = __builtin_amdgcn_mfma_f32_16x16x32_bf16(ah.b, bh[q].b, acc[rb][q], 0, 0, 0);
                    acc[rb][q] = __builtin_amdgcn_mfma_f32_16x16x32_bf16(ah.b, bl[q].b, acc[rb][q], 0, 0, 0);
                }
                if (gath) {
                    Frag al;
                    al.s = *(const s16x8*)(As_lo + sidx);
                    #pragma unroll
                    for (int q = 0; q < 2; ++q)
                        acc[rb][q] = __builtin_amdgcn_mfma_f32_16x16x32_bf16(al.b, bh[q].b, acc[rb][q], 0, 0, 0);
                }
            }
        }
    }

    // lane layout: col = (w*2+q)*16 + c ; row = rb*16 + hi4*4 + reg
    if (MODE == 0) {
        __syncthreads();
        #pragma unroll
        for (int rb = 0; rb < 2; ++rb)
            #pragma unroll
            for (int q = 0; q < 2; ++q) {
                int col = (w * 2 + q) * 16 + c;
                #pragma unroll
                for (int reg = 0; reg < 4; ++reg) {
                    int row = rb * 16 + hi4 * 4 + reg;
                    union { __bf16 b; unsigned short u; } cv;
                    cv.b = (__bf16)acc[rb][q][reg];
                    As_hi[row * HD + col] = cv.u;
                }
            }
        __syncthreads();
        int row = tid >> 3;
        int c8  = (tid & 7) * 8;
        int gr  = row0 + row;
        if (gr < s.M) {
            *(s16x8*)(s.out + (size_t)gr * HD + c8)      = *(const s16x8*)(As_hi + row * HD + c8);
            *(s16x8*)(s.out + (size_t)gr * HD + 64 + c8) = *(const s16x8*)(As_hi + row * HD + 64 + c8);
        }
        return;
    }

    float bsum_[2], gl[2], bb[2];
    #pragma unroll
    for (int q = 0; q < 2; ++q) {
        int col = (w * 2 + q) * 16 + c;
        float b = 0.f;
        if (s.bias0) b += s.bias0[col];
        if (s.bias1) b += s.bias1[col];
        bsum_[q] = b;
        gl[q] = s.g_ln[col];
        bb[q] = s.b_ln[col];
    }

    float v[2][2][4];
    #pragma unroll
    for (int rb = 0; rb < 2; ++rb)
        #pragma unroll
        for (int q = 0; q < 2; ++q) {
            int col = (w * 2 + q) * 16 + c;
            #pragma unroll
            for (int reg = 0; reg < 4; ++reg) {
                int row = rb * 16 + hi4 * 4 + reg;
                float r_ = 0.f;
                if (s.use_res) {
                    int sx = (row * HD + col) ^ ((row & 7) << 3);
                    union { __bf16 b; unsigned short u; } cb; cb.u = As_hi[sx];
                    r_ = (float)cb.b;
                }
                v[rb][q][reg] = (acc[rb][q][reg] + bsum_[q]) * s.scale + r_;
            }
        }

    #pragma unroll
    for (int rb = 0; rb < 2; ++rb)
        #pragma unroll
        for (int reg = 0; reg < 4; ++reg) {
            float sm = v[rb][0][reg] + v[rb][1][reg];
            float qq = v[rb][0][reg] * v[rb][0][reg] + v[rb][1][reg] * v[rb][1][reg];
            #pragma unroll
            for (int m = 1; m <= 8; m <<= 1) {
                sm += __shfl_xor(sm, m);
                qq += __shfl_xor(qq, m);
            }
            if (c == 0) {
                int row = rb * 16 + hi4 * 4 + reg;
                psum[w][row] = sm;
                psq[w][row]  = qq;
            }
        }
    __syncthreads();

    #pragma unroll
    for (int rb = 0; rb < 2; ++rb)
        #pragma unroll
        for (int reg = 0; reg < 4; ++reg) {
            int row = rb * 16 + hi4 * 4 + reg;
            float S  = psum[0][row] + psum[1][row] + psum[2][row] + psum[3][row];
            float Q  = psq[0][row]  + psq[1][row]  + psq[2][row]  + psq[3][row];
            float mean = S * (1.f / 128.f);
            float var  = Q * (1.f / 128.f) - mean * mean;
            float rstd = rsqrtf(var + 1e-5f);
            #pragma unroll
            for (int q = 0; q < 2; ++q) {
                int col = (w * 2 + q) * 16 + c;
                float t = (v[rb][q][reg] - mean) * rstd * gl[q] + bb[q];
                union { __bf16 b; unsigned short u; } cv;
                cv.b = (__bf16)gelu_f(t);
                As_hi[row * HD + col] = cv.u;
            }
        }
    __syncthreads();

    {
        int row = tid >> 3;
        int c8  = (tid & 7) * 8;
        int gr  = row0 + row;
        if (gr < s.M) {
            *(s16x8*)(s.out + (size_t)gr * HD + c8)      = *(const s16x8*)(As_hi + row * HD + c8);
            *(s16x8*)(s.out + (size_t)gr * HD + 64 + c8) = *(const s16x8*)(As_hi + row * HD + 64 + c8);
        }
    }
}

// merged pos+neg decoder: out[e] = dot(hc[src[e]], Q[dst[e]]) ; 16 lanes per edge
__global__ void edge_score2(const int* __restrict__ pos, const int* __restrict__ neg,
                            const unsigned short* __restrict__ Hc,
                            const unsigned short* __restrict__ Qb,
                            float* __restrict__ out)
{
    int t = blockIdx.x * blockDim.x + threadIdx.x;
    int e = t >> 4;
    if (e >= 2 * T_EP) return;
    int lane = t & 15;
    const int* ei = pos;
    float* o = out;
    if (e >= T_EP) { e -= T_EP; ei = neg; o = out + T_EP; }
    int sI = ei[e];
    int dI = ei[T_EP + e];
    Frag p, h;
    p.s = *(const s16x8*)(Hc + (size_t)sI * HD + lane * 8);
    h.s = *(const s16x8*)(Qb + (size_t)dI * HD + lane * 8);
    float acc = 0.f;
    #pragma unroll
    for (int j = 0; j < 8; ++j)
        acc += (float)p.b[j] * (float)h.b[j];
    #pragma unroll
    for (int m = 1; m <= 8; m <<= 1) acc += __shfl_xor(acc, m);
    if (lane == 0) o[e] = acc;
}

extern "C" void kernel_launch(void* const* d_in, const int* in_sizes, int n_in,
                              void* d_out, int out_size, void* d_ws, size_t ws_size,
                              hipStream_t stream)
{
    const float* x_chem    = (const float*)d_in[0];
    const float* x_dis     = (const float*)d_in[1];
    const float* gene_emb  = (const float*)d_in[2];
    const float* proj_W    = (const float*)d_in[3];
    const float* proj_b    = (const float*)d_in[4];
    const float* proj_ln_g = (const float*)d_in[5];
    const float* proj_ln_b = (const float*)d_in[6];
    const float* sage_Wl   = (const float*)d_in[7];
    const float* sage_bl   = (const float*)d_in[8];
    const float* sage_Wr   = (const float*)d_in[9];
    const float* ln_g      = (const float*)d_in[10];
    const float* ln_b      = (const float*)d_in[11];
    const float* W_cd      = (const float*)d_in[12];
    const int*   ei_c2d    = (const int*)d_in[13];
    const int*   ei_d2c    = (const int*)d_in[14];
    const int*   ei_c2g    = (const int*)d_in[15];
    const int*   ei_g2c    = (const int*)d_in[16];
    const int*   pos_edge  = (const int*)d_in[17];
    const int*   neg_edge  = (const int*)d_in[18];
    float* out = (float*)d_out;

    // ---- workspace layout (single bf16 plane per state, ping-pong) ----
    unsigned short* us = (unsigned short*)d_ws;
    const size_t SC = (size_t)T_NC * HD, SD = (size_t)T_ND * HD, SG = (size_t)T_NG * HD;
    unsigned short* hc0  = us;
    unsigned short* hc1  = hc0 + SC;
    unsigned short* hd0  = hc1 + SC;
    unsigned short* hd1  = hd0 + SD;
    unsigned short* hgA  = hd1 + SD;
    unsigned short* hgB  = hgA + SG;       // unused (layer-2 gene dropped); kept for layout
    unsigned short* geneB = hgB + SG;      // bf16 of gene_emb
    unsigned short* packHi = geneB + SG;
    unsigned short* packLo = packHi + (size_t)NMAT * HD * HD;
    int* ib  = (int*)(packLo + (size_t)NMAT * HD * HD);
    int* deg = ib;                  // DEGN
    int* fil = deg + DEGN;          // DEGN
    int* rp  = fil + DEGN;          // DEGN
    int* col = rp + DEGN;           // 4E
    int* bsum = col + 4 * T_E;      // 512
    unsigned short* Qb = hd1;       // Q = hd_final @ W_cd^T ; hd1 free after layer 2

    const dim3 blk(256);
    const int gC = (T_NC + 31) / 32;   // 3125
    const int gD = (T_ND + 31) / 32;   // 625
    const int gG = (T_NG + 31) / 32;   // 1563
    const int gE256 = (T_E + 255) / 256;
    const int gScan = (DEGN + 1023) / 1024;
    const int gConv = (int)(((size_t)T_NG * HD / 8 + 255) / 256);
    const int OFF_DC = 0, OFF_GC = T_NC, OFF_CD = 2 * T_NC, OFF_CG = 2 * T_NC + T_ND;

    // ---- one-time: pack weights, convert gene, build concatenated CSR ----
    pack_weights<<<NMAT, blk, 0, stream>>>(proj_W, sage_Wl, sage_Wr, W_cd, packHi, packLo);
    conv_gene<<<gConv, blk, 0, stream>>>(gene_emb, geneB);
    hipMemsetAsync(deg, 0, (size_t)2 * DEGN * sizeof(int), stream);  // deg + fil

    edge_count4<<<4 * gE256, blk, 0, stream>>>(ei_d2c, ei_g2c, ei_c2d, ei_c2g, gE256, deg);
    scan_local<<<gScan, blk, 0, stream>>>(deg, rp, bsum, DEGN);
    scan_tops<<<1, 64, 0, stream>>>(bsum, gScan);
    scan_add<<<gScan, blk, 0, stream>>>(rp, bsum, DEGN);
    edge_fill4<<<4 * gE256, blk, 0, stream>>>(ei_d2c, ei_g2c, ei_c2d, ei_c2g, gE256, rp, fil, col);

    Seg z{};  // empty (nblk=0)

    // ---- projections (merged dispatch) ----
    {
        Seg pc{};
        pc.p0.A = x_chem; pc.p0.w = 0; pc.p0.fmt = 0;
        pc.np = 1; pc.use_res = 0;
        pc.bias0 = proj_b; pc.g_ln = proj_ln_g; pc.b_ln = proj_ln_b;
        pc.scale = 1.f; pc.out = hc0; pc.M = T_NC; pc.nblk = gC;
        Seg pd{};
        pd.p0.A = x_dis; pd.p0.w = 1; pd.p0.fmt = 0;
        pd.np = 1; pd.use_res = 0;
        pd.bias0 = proj_b + HD; pd.g_ln = proj_ln_g + HD; pd.b_ln = proj_ln_b + HD;
        pd.scale = 1.f; pd.out = hd0; pd.M = T_ND; pd.nblk = gD;
        fused_gemm<1><<<gC + gD, blk, 0, stream>>>(pc, pd, z, packHi, packLo);
    }

    for (int l = 0; l < 2; ++l) {
        const float* bl = sage_bl + (size_t)l * 4 * HD;
        const float* lg = ln_g + (size_t)l * 3 * HD;
        const float* lb = ln_b + (size_t)l * 3 * HD;
        const int wl = 2 + l * 4;
        const int wr = 10 + l * 4;
        const int wsum = 19 + l;

        const unsigned short* hcC = (l == 0) ? hc0 : hc1;
        unsigned short*       hcN = (l == 0) ? hc1 : hc0;
        const unsigned short* hdC = (l == 0) ? hd0 : hd1;
        unsigned short*       hdN = (l == 0) ? hd1 : hd0;
        const unsigned short* hgC = (l == 0) ? geneB : hgA;

        // chem: 0.5*(mean_dc(hd)@Wl1 + bl1 + mean_gc(hg)@Wl3 + bl3 + hc@(Wr1+Wr3)) + hc
        Seg sc{};
        sc.p0.A = hdC; sc.p0.fmt = 1; sc.p0.rp = rp + OFF_DC; sc.p0.dg = deg + OFF_DC; sc.p0.col = col; sc.p0.w = wl + 1;
        sc.p1.A = hgC; sc.p1.fmt = 1; sc.p1.rp = rp + OFF_GC; sc.p1.dg = deg + OFF_GC; sc.p1.col = col; sc.p1.w = wl + 3;
        sc.p2.A = hcC; sc.p2.fmt = 1; sc.p2.w = wsum;
        sc.np = 3; sc.use_res = 1;
        sc.bias0 = bl + 1 * HD; sc.bias1 = bl + 3 * HD;
        sc.scale = 0.5f; sc.g_ln = lg; sc.b_ln = lb;
        sc.out = hcN; sc.M = T_NC; sc.nblk = gC;

        // dis: mean_cd(hc)@Wl0 + bl0 + hd@Wr0 + hd
        Seg sd{};
        sd.p0.A = hcC; sd.p0.fmt = 1; sd.p0.rp = rp + OFF_CD; sd.p0.dg = deg + OFF_CD; sd.p0.col = col; sd.p0.w = wl + 0;
        sd.p1.A = hdC; sd.p1.fmt = 1; sd.p1.w = wr + 0;
        sd.np = 2; sd.use_res = 1;
        sd.bias0 = bl + 0 * HD;
        sd.scale = 1.f; sd.g_ln = lg + HD; sd.b_ln = lb + HD;
        sd.out = hdN; sd.M = T_ND; sd.nblk = gD;

        if (l == 0) {
            // gene layer 0 only (layer-2 gene output is dead -> skipped)
            Seg sg{};
            sg.p0.A = hcC; sg.p0.fmt = 1; sg.p0.rp = rp + OFF_CG; sg.p0.dg = deg + OFF_CG; sg.p0.col = col; sg.p0.w = wl + 2;
            sg.p1.A = hgC; sg.p1.fmt = 1; sg.p1.w = wr + 2;
            sg.np = 2; sg.use_res = 1;
            sg.bias0 = bl + 2 * HD;
            sg.scale = 1.f; sg.g_ln = lg + 2 * HD; sg.b_ln = lb + 2 * HD;
            sg.out = hgA; sg.M = T_NG; sg.nblk = gG;
            fused_gemm<1><<<gC + gD + gG, blk, 0, stream>>>(sc, sd, sg, packHi, packLo);
        } else {
            fused_gemm<1><<<gC + gD, blk, 0, stream>>>(sc, sd, z, packHi, packLo);
        }
    }

    // Q = hd_final @ W_cd^T  (hd_final = hd0; 625 blocks vs 3125 for the P-side form)
    {
        Seg sq{};
        sq.p0.A = hd0; sq.p0.fmt = 1; sq.p0.w = 18;
        sq.np = 1; sq.use_res = 0;
        sq.scale = 1.f; sq.out = Qb; sq.M = T_ND; sq.nblk = gD;
        fused_gemm<0><<<gD, blk, 0, stream>>>(sq, z, z, packHi, packLo);
    }

    const int gEdge = (2 * T_EP * 16 + 255) / 256;
    edge_score2<<<gEdge, blk, 0, stream>>>(pos_edge, neg_edge, hc0, Qb, out);
}